// Round 7
// baseline (878.992 us; speedup 1.0000x reference)
//
#include <hip/hip_runtime.h>

#define C 16
#define TAPS 27
#define NCONV 17
#define LISTCAP 131072
#define BSZ 128            // conv block size (2 waves)
#define VPB (2 * BSZ)      // voxels per conv block

// ---- weight transpose: W[l][co][ci][tap] -> Wt[l][tap][ci][co] ----
__global__ void transpose_w_kernel(const float* __restrict__ W, float* __restrict__ Wt) {
    int i = blockIdx.x * blockDim.x + threadIdx.x;
    const int total = NCONV * TAPS * C * C;
    if (i >= total) return;
    int co = i & 15;
    int ci = (i >> 4) & 15;
    int rest = i >> 8;
    int tap = rest % TAPS;
    int l = rest / TAPS;
    Wt[i] = W[(((long)l * C + co) * C + ci) * TAPS + tap];
}

// ---- x: NCDHW -> NDHWC ----
__global__ void transpose_in_kernel(const float* __restrict__ x, float* __restrict__ xt, int n) {
    int v = blockIdx.x * blockDim.x + threadIdx.x;
    if (v >= n) return;
    float a[C];
#pragma unroll
    for (int ci = 0; ci < C; ci++) a[ci] = x[(long)ci * n + v];
    float4* dp = reinterpret_cast<float4*>(xt + (long)v * C);
    dp[0] = make_float4(a[0], a[1], a[2], a[3]);
    dp[1] = make_float4(a[4], a[5], a[6], a[7]);
    dp[2] = make_float4(a[8], a[9], a[10], a[11]);
    dp[3] = make_float4(a[12], a[13], a[14], a[15]);
}

// ---- NDHWC -> NCDHW (stage outputs into d_out) ----
__global__ void to_ncdhw_kernel(const float* __restrict__ src, float* __restrict__ dst, int n) {
    int v = blockIdx.x * blockDim.x + threadIdx.x;
    if (v >= n) return;
    const float4* sp = reinterpret_cast<const float4*>(src + (long)v * C);
    float4 q0 = sp[0], q1 = sp[1], q2 = sp[2], q3 = sp[3];
    dst[0L * n + v] = q0.x;  dst[1L * n + v] = q0.y;
    dst[2L * n + v] = q0.z;  dst[3L * n + v] = q0.w;
    dst[4L * n + v] = q1.x;  dst[5L * n + v] = q1.y;
    dst[6L * n + v] = q1.z;  dst[7L * n + v] = q1.w;
    dst[8L * n + v] = q2.x;  dst[9L * n + v] = q2.y;
    dst[10L * n + v] = q2.z; dst[11L * n + v] = q2.w;
    dst[12L * n + v] = q3.x; dst[13L * n + v] = q3.y;
    dst[14L * n + v] = q3.z; dst[15L * n + v] = q3.w;
}

// ---- ordered compaction: counts -> scan -> scatter ----
__global__ void count_kernel(const int* __restrict__ mi, int* __restrict__ counts, int n) {
    int i = blockIdx.x * 256 + threadIdx.x;
    int act = (i < n) && (mi[i] == 0);
    unsigned long long b = __ballot(act);
    __shared__ int wsum[4];
    int wid = threadIdx.x >> 6, lane = threadIdx.x & 63;
    if (lane == 0) wsum[wid] = __popcll(b);
    __syncthreads();
    if (threadIdx.x == 0) counts[blockIdx.x] = wsum[0] + wsum[1] + wsum[2] + wsum[3];
}

__global__ void scan_kernel(const int* __restrict__ counts, int* __restrict__ offsets,
                            int* __restrict__ nact, int nb) {
    __shared__ int s[256];
    int t = threadIdx.x;
    const int CH = (nb + 255) / 256;
    int base = t * CH, sum = 0;
    for (int j = 0; j < CH; j++)
        if (base + j < nb) sum += counts[base + j];
    s[t] = sum;
    __syncthreads();
    for (int off = 1; off < 256; off <<= 1) {
        int v = (t >= off) ? s[t - off] : 0;
        __syncthreads();
        s[t] += v;
        __syncthreads();
    }
    int run = s[t] - sum;  // exclusive base
    for (int j = 0; j < CH; j++) {
        if (base + j < nb) {
            offsets[base + j] = run;
            run += counts[base + j];
        }
    }
    if (t == 255) *nact = s[255];
}

__global__ void scatter_kernel(const int* __restrict__ mi, const int* __restrict__ offsets,
                               int* __restrict__ list, int n, int cap) {
    int i = blockIdx.x * 256 + threadIdx.x;
    int act = (i < n) && (mi[i] == 0);
    unsigned long long b = __ballot(act);
    __shared__ int wsum[4];
    int wid = threadIdx.x >> 6, lane = threadIdx.x & 63;
    if (lane == 0) wsum[wid] = __popcll(b);
    __syncthreads();
    int wbase = 0;
    for (int w = 0; w < wid; w++) wbase += wsum[w];
    int prefix = __popcll(b & ((1ull << lane) - 1));
    if (act) {
        int pos = offsets[blockIdx.x] + wbase + prefix;
        if (pos < cap) list[pos] = i;
    }
}

// ---- mask maxpool (2x2x2 stride, 3^3 window) ----
template <bool FROM_INT>
__global__ void pool_mask_kernel(const int* __restrict__ mi, const float* __restrict__ mf,
                                 float* __restrict__ mout, int Din, int Dout) {
    int i = blockIdx.x * blockDim.x + threadIdx.x;
    int n = Dout * Dout * Dout;
    if (i >= n) return;
    int x = i % Dout, y = (i / Dout) % Dout, z = i / (Dout * Dout);
    float v = 0.f;
    for (int kz = 0; kz < 3; kz++) {
        int zz = 2 * z - 1 + kz;
        if (zz < 0 || zz >= Din) continue;
        for (int ky = 0; ky < 3; ky++) {
            int yy = 2 * y - 1 + ky;
            if (yy < 0 || yy >= Din) continue;
            for (int kx = 0; kx < 3; kx++) {
                int xx = 2 * x - 1 + kx;
                if (xx < 0 || xx >= Din) continue;
                long idx = ((long)zz * Din + yy) * Din + xx;
                float mv = FROM_INT ? ((mi[idx] == 0) ? 1.f : 0.f) : mf[idx];
                v = fmaxf(v, mv);
            }
        }
    }
    mout[i] = v;
}

// ---- conv in NDHWC; 2 voxels/thread, all 16 output channels ----
// MLP: all 8 float4 inputs of a tap are loaded before any FMA consumes them.
// Spill control: kx loop forced NOT unrolled (#pragma unroll 1) so only one
// tap's 8 quads are ever live; accumulators indexed by compile-time constants.
#define FMA16(A0, A1, CI)                                     \
    {                                                         \
        const float* wr_ = wt + (CI) * C;                     \
        _Pragma("unroll") for (int co_ = 0; co_ < C; co_++) { \
            float w_ = wr_[co_];                              \
            acc0[co_] += (A0) * w_;                           \
            acc1[co_] += (A1) * w_;                           \
        }                                                     \
    }

template <int STRIDE, bool SPARSE>
__global__ __launch_bounds__(BSZ) void conv_kernel(
    const float* __restrict__ in, float* __restrict__ out,
    const float* __restrict__ mask, const int* __restrict__ list,
    const int* __restrict__ nact, const float* __restrict__ Wt,
    const float* __restrict__ bs, const float* __restrict__ bb,
    int Din, int Dout) {
    int n = Dout * Dout * Dout;
    int nv = SPARSE ? *nact : n;
    if (SPARSE && nv > LISTCAP) nv = LISTCAP;
    if ((int)(blockIdx.x * VPB) >= nv) return;  // uniform whole-block early exit

    __shared__ float wl[TAPS * C * C];
    __shared__ float sc[C], bi[C];
    int tid = threadIdx.x;
    {
        const float4* ws4 = reinterpret_cast<const float4*>(Wt);
        float4* wl4 = reinterpret_cast<float4*>(wl);
        for (int idx = tid; idx < TAPS * C * C / 4; idx += BSZ) wl4[idx] = ws4[idx];
        if (tid < C) { sc[tid] = bs[tid]; bi[tid] = bb[tid]; }
    }
    __syncthreads();

    int s0 = blockIdx.x * VPB + tid;
    int s1 = s0 + BSZ;
    bool val0 = s0 < nv, val1 = s1 < nv;
    int v0 = 0, v1 = 0;
    if (SPARSE) {
        if (val0) v0 = list[s0];
        if (val1) v1 = list[s1];
    } else {
        v0 = val0 ? s0 : 0;
        v1 = val1 ? s1 : 0;
    }
    int x0 = v0 % Dout, y0 = (v0 / Dout) % Dout, z0 = v0 / (Dout * Dout);
    int x1 = v1 % Dout, y1 = (v1 / Dout) % Dout, z1 = v1 / (Dout * Dout);
    float mk0 = SPARSE ? 1.f : (val0 ? mask[v0] : 0.f);
    float mk1 = SPARSE ? 1.f : (val1 ? mask[v1] : 0.f);

    float acc0[C], acc1[C];
#pragma unroll
    for (int co = 0; co < C; co++) { acc0[co] = 0.f; acc1[co] = 0.f; }

    const float4 z4 = make_float4(0.f, 0.f, 0.f, 0.f);
#pragma unroll 1
    for (int kz = 0; kz < 3; kz++) {
        int zz0 = STRIDE * z0 - 1 + kz;
        int zz1 = STRIDE * z1 - 1 + kz;
#pragma unroll 1
        for (int ky = 0; ky < 3; ky++) {
            int yy0 = STRIDE * y0 - 1 + ky;
            int yy1 = STRIDE * y1 - 1 + ky;
#pragma unroll 1
            for (int kx = 0; kx < 3; kx++) {
                int xx0 = STRIDE * x0 - 1 + kx;
                int xx1 = STRIDE * x1 - 1 + kx;
                bool ok0 = ((unsigned)zz0 < (unsigned)Din) && ((unsigned)yy0 < (unsigned)Din) &&
                           ((unsigned)xx0 < (unsigned)Din);
                bool ok1 = ((unsigned)zz1 < (unsigned)Din) && ((unsigned)yy1 < (unsigned)Din) &&
                           ((unsigned)xx1 < (unsigned)Din);
                // issue all 8 loads before any FMA (MLP within the tap)
                float4 A0 = z4, A1 = z4, A2 = z4, A3 = z4;
                float4 B0 = z4, B1 = z4, B2 = z4, B3 = z4;
                if (ok0) {
                    const float4* p0 = reinterpret_cast<const float4*>(
                        in + (long)((zz0 * Din + yy0) * Din + xx0) * C);
                    A0 = p0[0]; A1 = p0[1]; A2 = p0[2]; A3 = p0[3];
                }
                if (ok1) {
                    const float4* p1 = reinterpret_cast<const float4*>(
                        in + (long)((zz1 * Din + yy1) * Din + xx1) * C);
                    B0 = p1[0]; B1 = p1[1]; B2 = p1[2]; B3 = p1[3];
                }
                const float* wt = &wl[((kz * 3 + ky) * 3 + kx) * C * C];
                FMA16(A0.x, B0.x, 0)
                FMA16(A0.y, B0.y, 1)
                FMA16(A0.z, B0.z, 2)
                FMA16(A0.w, B0.w, 3)
                FMA16(A1.x, B1.x, 4)
                FMA16(A1.y, B1.y, 5)
                FMA16(A1.z, B1.z, 6)
                FMA16(A1.w, B1.w, 7)
                FMA16(A2.x, B2.x, 8)
                FMA16(A2.y, B2.y, 9)
                FMA16(A2.z, B2.z, 10)
                FMA16(A2.w, B2.w, 11)
                FMA16(A3.x, B3.x, 12)
                FMA16(A3.y, B3.y, 13)
                FMA16(A3.z, B3.z, 14)
                FMA16(A3.w, B3.w, 15)
            }
        }
    }

    if (val0) {
        float r[4];
        float4* o4 = reinterpret_cast<float4*>(out + (long)v0 * C);
#pragma unroll
        for (int q = 0; q < 4; q++) {
#pragma unroll
            for (int j = 0; j < 4; j++) {
                int co = q * 4 + j;
                r[j] = fmaxf(acc0[co] * sc[co] + bi[co], 0.f) * mk0;
            }
            o4[q] = make_float4(r[0], r[1], r[2], r[3]);
        }
    }
    if (val1) {
        float r[4];
        float4* o4 = reinterpret_cast<float4*>(out + (long)v1 * C);
#pragma unroll
        for (int q = 0; q < 4; q++) {
#pragma unroll
            for (int j = 0; j < 4; j++) {
                int co = q * 4 + j;
                r[j] = fmaxf(acc1[co] * sc[co] + bi[co], 0.f) * mk1;
            }
            o4[q] = make_float4(r[0], r[1], r[2], r[3]);
        }
    }
}

extern "C" void kernel_launch(void* const* d_in, const int* in_sizes, int n_in,
                              void* d_out, int out_size, void* d_ws, size_t ws_size,
                              hipStream_t stream) {
    const float* x = (const float*)d_in[0];
    const int* mask_idx = (const int*)d_in[1];
    const float* W = (const float*)d_in[2];
    const float* bs = (const float*)d_in[3];
    const float* bb = (const float*)d_in[4];
    float* out = (float*)d_out;
    float* ws = (float*)d_ws;

    const int n96 = 96 * 96 * 96;  // 884736
    const int n48 = 48 * 48 * 48;  // 110592
    const int n24 = 24 * 24 * 24;  // 13824
    const int n12 = 12 * 12 * 12;  // 1728
    const int n6 = 6 * 6 * 6;      // 216
    const int NB = (n96 + 255) / 256;  // 3456

    float* P0 = ws;                  // xt, then ping-pong
    float* P1 = P0 + (long)C * n96;  // ping-pong (pre-zeroed for sparse scatter)
    float* m48 = P1 + (long)C * n96;
    float* m24 = m48 + n48;
    float* m12 = m24 + n24;
    float* m6 = m12 + n12;
    float* Wt = m6 + n6;
    int* list = (int*)(Wt + (long)NCONV * TAPS * C * C);
    int* counts = list + LISTCAP;
    int* offsets = counts + NB;
    int* nact = offsets + NB;

    const int BS = 256;
    auto blk = [&](long t) { return dim3((unsigned)((t + BS - 1) / BS)); };
    auto cblk = [&](long nvox) { return dim3((unsigned)((nvox + VPB - 1) / VPB)); };

    hipMemsetAsync(P1, 0, (long)C * n96 * sizeof(float), stream);
    hipLaunchKernelGGL(transpose_w_kernel, blk(NCONV * TAPS * C * C), dim3(BS), 0, stream, W, Wt);
    hipLaunchKernelGGL(transpose_in_kernel, blk(n96), dim3(BS), 0, stream, x, P0, n96);
    hipLaunchKernelGGL(count_kernel, dim3(NB), dim3(BS), 0, stream, mask_idx, counts, n96);
    hipLaunchKernelGGL(scan_kernel, dim3(1), dim3(BS), 0, stream, counts, offsets, nact, NB);
    hipLaunchKernelGGL(scatter_kernel, dim3(NB), dim3(BS), 0, stream, mask_idx, offsets, list,
                       n96, LISTCAP);

    auto sconv = [&](const float* in, float* op, int layer) {
        hipLaunchKernelGGL((conv_kernel<1, true>), cblk(LISTCAP), dim3(BSZ), 0, stream,
                           in, op, (const float*)nullptr, list, nact,
                           Wt + (long)layer * TAPS * C * C, bs + layer * C, bb + layer * C, 96, 96);
    };
    auto subm = [&](const float* in, float* op, const float* m, int layer, int D) {
        int n = D * D * D;
        hipLaunchKernelGGL((conv_kernel<1, false>), cblk(n), dim3(BSZ), 0, stream,
                           in, op, m, list, nact, Wt + (long)layer * TAPS * C * C,
                           bs + layer * C, bb + layer * C, D, D);
    };
    auto down = [&](const float* in, float* op, const float* m, int layer, int Dout) {
        int n = Dout * Dout * Dout;
        hipLaunchKernelGGL((conv_kernel<2, false>), cblk(n), dim3(BSZ), 0, stream,
                           in, op, m, list, nact, Wt + (long)layer * TAPS * C * C,
                           bs + layer * C, bb + layer * C, 2 * Dout, Dout);
    };

    // masks
    hipLaunchKernelGGL((pool_mask_kernel<true>), blk(n48), dim3(BS), 0, stream,
                       mask_idx, (const float*)nullptr, m48, 96, 48);
    hipLaunchKernelGGL((pool_mask_kernel<false>), blk(n24), dim3(BS), 0, stream,
                       (const int*)nullptr, m48, m24, 48, 24);
    hipLaunchKernelGGL((pool_mask_kernel<false>), blk(n12), dim3(BS), 0, stream,
                       (const int*)nullptr, m24, m12, 24, 12);
    hipLaunchKernelGGL((pool_mask_kernel<false>), blk(n6), dim3(BS), 0, stream,
                       (const int*)nullptr, m12, m6, 12, 6);

    // Stage @96 (sparse). L0: P0(xt) -> P1 (zeroed). L1: P1 -> P0 (inactive already 0 from x*mask).
    sconv(P0, P1, 0);
    sconv(P1, P0, 1);
    // 48 level (dense, ~94% mask)
    down(P0, P1, m48, 2, 48);
    subm(P1, P0, m48, 3, 48);
    subm(P0, P1, m48, 4, 48);  // net1 in P1
    hipLaunchKernelGGL(to_ncdhw_kernel, blk(n48), dim3(BS), 0, stream, P1, out, n48);
    // 24 level
    down(P1, P0, m24, 5, 24);
    subm(P0, P1, m24, 6, 24);
    subm(P1, P0, m24, 7, 24);
    subm(P0, P1, m24, 8, 24);  // net2 in P1
    hipLaunchKernelGGL(to_ncdhw_kernel, blk(n24), dim3(BS), 0, stream, P1, out + (long)C * n48, n24);
    // 12 level
    down(P1, P0, m12, 9, 12);
    subm(P0, P1, m12, 10, 12);
    subm(P1, P0, m12, 11, 12);
    subm(P0, P1, m12, 12, 12);  // net3 in P1
    hipLaunchKernelGGL(to_ncdhw_kernel, blk(n12), dim3(BS), 0, stream, P1,
                       out + (long)C * (n48 + n24), n12);
    // 6 level
    down(P1, P0, m6, 13, 6);
    subm(P0, P1, m6, 14, 6);
    subm(P1, P0, m6, 15, 6);
    subm(P0, P1, m6, 16, 6);  // net4 in P1
    hipLaunchKernelGGL(to_ncdhw_kernel, blk(n6), dim3(BS), 0, stream, P1,
                       out + (long)C * (n48 + n24 + n12), n6);
}